// Round 5
// baseline (203.688 us; speedup 1.0000x reference)
//
#include <hip/hip_runtime.h>
#include <hip/hip_bf16.h>
#include <stdint.h>

typedef __bf16 bf16x8 __attribute__((ext_vector_type(8)));
typedef float  f32x4  __attribute__((ext_vector_type(4)));
typedef float  f32x16 __attribute__((ext_vector_type(16)));

// ---------- helpers ----------

__device__ __forceinline__ uint32_t rn2_bf16(uint32_t lo, uint32_t hi) {
  uint32_t rlo = (lo + 0x7FFFu + ((lo >> 16) & 1u)) >> 16;
  uint32_t rhi = (hi + 0x7FFFu + ((hi >> 16) & 1u)) >> 16;
  return (rhi << 16) | (rlo & 0xFFFFu);
}

__device__ __forceinline__ uint32_t sign2_bf16(uint32_t lo, uint32_t hi) {
  uint32_t slo = (lo & 0x7FFFFFFFu) ? (0x3F80u | ((lo >> 16) & 0x8000u)) : 0u;
  uint32_t shi = (hi & 0x7FFFFFFFu) ? (0x3F80u | ((hi >> 16) & 0x8000u)) : 0u;
  return (shi << 16) | slo;
}

__device__ __forceinline__ void gl16(const void* g, void* l) {
  __builtin_amdgcn_global_load_lds(
      (const __attribute__((address_space(1))) uint32_t*)g,
      (__attribute__((address_space(3))) uint32_t*)l,
      16, 0, 0);
}

// ---------- fused prep kernel: X -> bf16 (RN), W -> sign bf16 ----------

__global__ void cvt_prep(const uint4* __restrict__ x, uint4* __restrict__ xo, int nx8,
                         const uint4* __restrict__ w, uint4* __restrict__ wo, int nw8) {
  int stride = gridDim.x * blockDim.x;
  int total = nx8 + nw8;
  for (int i = blockIdx.x * blockDim.x + threadIdx.x; i < total; i += stride) {
    if (i < nx8) {
      uint4 a = x[2 * i + 0];
      uint4 b = x[2 * i + 1];
      uint4 o;
      o.x = rn2_bf16(a.x, a.y);
      o.y = rn2_bf16(a.z, a.w);
      o.z = rn2_bf16(b.x, b.y);
      o.w = rn2_bf16(b.z, b.w);
      xo[i] = o;
    } else {
      int j = i - nx8;
      uint4 a = w[2 * j + 0];
      uint4 b = w[2 * j + 1];
      uint4 o;
      o.x = sign2_bf16(a.x, a.y);
      o.y = sign2_bf16(a.z, a.w);
      o.z = sign2_bf16(b.x, b.y);
      o.w = sign2_bf16(b.z, b.w);
      wo[j] = o;
    }
  }
}

// ---------- 256x256 GEMM, 32x32x16 MFMA, fragment-linear LDS ----------
// C[M][N] = A[M][K] * B[N][K]^T + bias.  BM=BN=256, BK=64, 8 waves (2Mx4N),
// wave tile 128x64.  MFMA 32x32x16 bf16 (2495 TF pipe vs 2176 for 16x16).
// LDS 128 KiB = 2 bufs x 64 KB. Buf layout is FRAGMENT-LINEAR: A region 32KB
// holds frag(mb 0..7, ks 0..3) at (mb*4+ks)*1024 + lane*16; B region ditto at
// +32768 (nb over 256 cols). Staging writes each 1KB fragment with one gl16
// whose per-lane GLOBAL address gathers that fragment's elements:
//   lane l of A-frag(mb,ks) = A[row = mb*32 + (l&31)][k = ks*16 + (l>>5)*8 ..+8]
// so ds_reads are base+lane*16+imm — conflict-free by construction, no swizzle.
// Operand layout (family of R1-verified 16x16): A row=l&31, k=(l>>5)*8+j;
// B col=l&31, same k.  C/D: col=lane&31, row=(reg&3)+8*(reg>>2)+4*(lane>>5)
// (m74/m101-verified).
// Pipeline: 4 phases per K64-tile (one ks each): MFMA ks=q consumes frags read
// last phase; reads ks=q+1; STG/VM0 schedule identical to R4 (race-audited):
//   A0 staged ph5 (last read ph4-prev... see per-phase comments), VM0 at
//   ph3/ph7 drains the incoming tile (issued 2-3 phases earlier > HBM lat).

#define BARX()  asm volatile("s_barrier" ::: "memory")
#define VM0()   asm volatile("s_waitcnt vmcnt(0)" ::: "memory")
#define VMN4()  asm volatile("s_waitcnt vmcnt(4)" ::: "memory")

__global__ __launch_bounds__(512, 2) void gemm256(
    const uint16_t* __restrict__ A,  // [M][K] bf16 bits
    const uint16_t* __restrict__ B,  // [N][K] bf16 bits (sign values)
    const float* __restrict__ bias,  // [N]
    float* __restrict__ C,           // [M][N] f32
    int M, int N, int K) {
  __shared__ alignas(16) uint8_t L[131072];
  uint8_t* Lb = L;

  const int tid  = threadIdx.x;
  const int lane = tid & 63;
  const int w    = tid >> 6;
  const int wr   = w >> 2;        // 0..1  -> M rows [wr*128, +128)
  const int wc   = w & 3;         // 0..3  -> N cols [wc*64, +64)
  const int l31  = lane & 31;
  const int lhi  = lane >> 5;     // k-half
  const int lds16 = lane * 16;

  // bijective XCD swizzle (nwg % 8 == 0 guaranteed by launcher)
  const int nbx = N >> 8;
  const int nwg = nbx * (M >> 8);
  const int bid = blockIdx.x;
  const int swb = (bid & 7) * (nwg >> 3) + (bid >> 3);
  const size_t m0 = (size_t)(swb / nbx) << 8;
  const size_t n0 = (size_t)(swb % nbx) << 8;

  const int NT = K >> 6;              // BK=64 tiles
  const size_t rowB = (size_t)K * 2;  // global row stride in bytes

  // staging: wave w stages frags f=2w, 2w+1 of each 16KB half:
  // mb = w>>1, ks = (w&1)*2 and +1.  Per-lane gather address:
  const size_t vStg = (size_t)((w >> 1) * 32 + l31) * rowB + (w & 1) * 64 + lhi * 16;
  const int dStg = w * 2048;          // LDS dest: frag 2w at +0, 2w+1 at +1024

  const char* Ab = (const char*)A + m0 * rowB;
  const char* Bb = (const char*)B + n0 * rowB;
  const size_t hiO = (size_t)128 * rowB;  // +128 rows (second half)

#define STG(LOFF, SRC) do { \
    gl16((SRC) + vStg, Lb + (LOFF) + dStg); \
    gl16((SRC) + vStg + 32, Lb + (LOFF) + dStg + 1024); } while (0)

  // fragment reads: linear, base + imm
#define FRA32(d, i, q) (*reinterpret_cast<const bf16x8*>( \
    Lb + (d) * 65536 + wr * 16384 + (i) * 4096 + (q) * 1024 + lds16))
#define FRB32(d, j, q) (*reinterpret_cast<const bf16x8*>( \
    Lb + (d) * 65536 + 32768 + wc * 8192 + (j) * 4096 + (q) * 1024 + lds16))

#define RDA(DST, d, q) do { \
    _Pragma("unroll") \
    for (int i = 0; i < 4; ++i) DST[i] = FRA32(d, i, q); } while (0)
#define RDB(DST, d, q) do { \
    _Pragma("unroll") \
    for (int j = 0; j < 2; ++j) DST[j] = FRB32(d, j, q); } while (0)

  f32x16 acc[4][2] = {};

#define QM(A4, B2) do { \
    __builtin_amdgcn_s_setprio(1); \
    _Pragma("unroll") \
    for (int i = 0; i < 4; ++i) \
      _Pragma("unroll") \
      for (int j = 0; j < 2; ++j) \
        acc[i][j] = __builtin_amdgcn_mfma_f32_32x32x16_bf16( \
            A4[i], B2[j], acc[i][j], 0, 0, 0); \
    __builtin_amdgcn_s_setprio(0); } while (0)

  // ---- prologue: tile0 (A+B) -> buf0, tile1 B -> buf1 ----
  STG(0,      Ab);              // A0-lo (mb 0-3)
  STG(16384,  Ab + hiO);        // A0-hi (mb 4-7)
  STG(32768,  Bb);              // B0-lo
  STG(49152,  Bb + hiO);        // B0-hi
  STG(98304,  Bb + 128);        // B1-lo (tile 1 = col byte offset 128)
  STG(114688, Bb + hiO + 128);  // B1-hi
  VMN4();   // tile0's 8 loads landed; B1's 4 still in flight
  BARX();

  bf16x8 aP[4], aQ[4], bP[2], bQ[2];
  RDA(aP, 0, 0);
  RDB(bP, 0, 0);

  const int T = K >> 7;  // iterations of 2 K-tiles
  for (int t = 0; t < T; ++t) {
    const size_t c1 = (size_t)(2 * t + 1) * 128;
    const int k2i = 2 * t + 2, k3i = 2 * t + 3;
    const size_t c2 = (size_t)(k2i < NT ? k2i : NT - 1) * 128;
    const size_t c3 = (size_t)(k3i < NT ? k3i : NT - 1) * 128;

    // ph1: MFMA buf0 ks0; read buf0 ks1; stage A(t1)->buf1-A
    QM(aP, bP);
    RDA(aQ, 0, 1); RDB(bQ, 0, 1);
    STG(65536, Ab + c1);
    STG(81920, Ab + hiO + c1);
    BARX();

    // ph2: MFMA ks1; read ks2
    QM(aQ, bQ);
    RDA(aP, 0, 2); RDB(bP, 0, 2);
    BARX();

    // ph3: MFMA ks2; read ks3; VM0 drains t1 (B1 staged ph8-prev, A1 ph1)
    QM(aP, bP);
    RDA(aQ, 0, 3); RDB(bQ, 0, 3);
    VM0();
    BARX();

    // ph4: MFMA ks3; read buf1 ks0; stage B(t2)->buf0-B
    QM(aQ, bQ);
    RDA(aP, 1, 0); RDB(bP, 1, 0);
    STG(32768, Bb + c2);
    STG(49152, Bb + hiO + c2);
    BARX();

    // ph5: MFMA buf1 ks0; read buf1 ks1; stage A(t2)->buf0-A
    QM(aP, bP);
    RDA(aQ, 1, 1); RDB(bQ, 1, 1);
    STG(0, Ab + c2);
    STG(16384, Ab + hiO + c2);
    BARX();

    // ph6: MFMA ks1; read ks2
    QM(aQ, bQ);
    RDA(aP, 1, 2); RDB(bP, 1, 2);
    BARX();

    // ph7: MFMA ks2; read ks3; VM0 drains t2 (B ph4, A ph5)
    QM(aP, bP);
    RDA(aQ, 1, 3); RDB(bQ, 1, 3);
    VM0();
    BARX();

    // ph8: MFMA ks3; read buf0(t2) ks0; stage B(t3)->buf1-B
    QM(aQ, bQ);
    RDA(aP, 0, 0); RDB(bP, 0, 0);
    STG(98304, Bb + c3);
    STG(114688, Bb + hiO + c3);
    BARX();
  }

  // ---- epilogue: +bias, f32 store ----
  // C/D 32x32: col = lane&31, row = (reg&3) + 8*(reg>>2) + 4*(lane>>5)
#pragma unroll
  for (int i = 0; i < 4; ++i) {
#pragma unroll
    for (int j2 = 0; j2 < 2; ++j2) {
      const size_t col = n0 + wc * 64 + j2 * 32 + l31;
      const float bv = bias[col];
      const size_t rbase = m0 + wr * 128 + i * 32 + lhi * 4;
#pragma unroll
      for (int r = 0; r < 16; ++r) {
        const size_t row = rbase + (r & 3) + 8 * (r >> 2);
        C[row * N + col] = acc[i][j2][r] + bv;
      }
    }
  }
}

// ---------- round-1 128x128 kernel (fallback, known-good) ----------

__global__ __launch_bounds__(256) void gemm_bin(
    const uint16_t* __restrict__ A, const uint16_t* __restrict__ B,
    const float* __restrict__ bias, float* __restrict__ C,
    int M, int N, int K) {
  constexpr int BK = 32;
  __shared__ alignas(16) uint16_t lA[128 * BK];
  __shared__ alignas(16) uint16_t lB[128 * BK];
  const int tid = threadIdx.x;
  const int lane = tid & 63;
  const int wid = tid >> 6;
  const int wr = wid >> 1, wc = wid & 1;
  const int r16 = lane & 15, kg = lane >> 4;
  const int m0 = blockIdx.y * 128, n0 = blockIdx.x * 128;
  f32x4 acc[4][4] = {};
  for (int k0 = 0; k0 < K; k0 += BK) {
    __syncthreads();
#pragma unroll
    for (int p = 0; p < 2; ++p) {
      int idx = p * 256 + tid;
      int row = idx >> 2;
      int col = (idx & 3) * 8;
      gl16(A + (size_t)(m0 + row) * K + k0 + col, lA + p * 2048 + wid * 512);
      gl16(B + (size_t)(n0 + row) * K + k0 + col, lB + p * 2048 + wid * 512);
    }
    __syncthreads();
    bf16x8 af[4], bg[4];
#pragma unroll
    for (int i = 0; i < 4; ++i)
      af[i] = *reinterpret_cast<const bf16x8*>(lA + (wr * 64 + i * 16 + r16) * BK + kg * 8);
#pragma unroll
    for (int i = 0; i < 4; ++i)
      bg[i] = *reinterpret_cast<const bf16x8*>(lB + (wc * 64 + i * 16 + r16) * BK + kg * 8);
#pragma unroll
    for (int mi = 0; mi < 4; ++mi)
#pragma unroll
      for (int ni = 0; ni < 4; ++ni)
        acc[mi][ni] = __builtin_amdgcn_mfma_f32_16x16x32_bf16(af[mi], bg[ni], acc[mi][ni], 0, 0, 0);
  }
#pragma unroll
  for (int ni = 0; ni < 4; ++ni) {
    int col = n0 + wc * 64 + ni * 16 + r16;
    float bv = bias[col];
#pragma unroll
    for (int mi = 0; mi < 4; ++mi) {
      int row0 = m0 + wr * 64 + mi * 16 + kg * 4;
#pragma unroll
      for (int j = 0; j < 4; ++j)
        C[(size_t)(row0 + j) * N + col] = acc[mi][ni][j] + bv;
    }
  }
}

__global__ void gemm_naive(const float* __restrict__ x, const float* __restrict__ w,
                           const float* __restrict__ b, float* __restrict__ out,
                           int M, int N, int K) {
  int n = blockIdx.x * blockDim.x + threadIdx.x;
  int m = blockIdx.y;
  if (n >= N || m >= M) return;
  float acc = 0.f;
  for (int k = 0; k < K; ++k) {
    float wv = w[(size_t)n * K + k];
    float s = (wv > 0.f) ? 1.f : ((wv < 0.f) ? -1.f : 0.f);
    acc += x[(size_t)m * K + k] * s;
  }
  out[(size_t)m * N + n] = acc + b[n];
}

extern "C" void kernel_launch(void* const* d_in, const int* in_sizes, int n_in,
                              void* d_out, int out_size, void* d_ws, size_t ws_size,
                              hipStream_t stream) {
  const float* x = (const float*)d_in[0];
  const float* w = (const float*)d_in[1];
  const float* b = (const float*)d_in[2];
  float* out = (float*)d_out;

  const int N = in_sizes[2];
  const int K = in_sizes[1] / N;
  const int M = in_sizes[0] / K;

  const size_t need = ((size_t)M * K + (size_t)N * K) * sizeof(uint16_t);
  if (ws_size < need) {
    hipLaunchKernelGGL(gemm_naive, dim3((N + 255) / 256, M), dim3(256), 0, stream,
                       x, w, b, out, M, N, K);
    return;
  }

  uint16_t* Xb = (uint16_t*)d_ws;
  uint16_t* Wb = Xb + (size_t)M * K;

  hipLaunchKernelGGL(cvt_prep, dim3(2048), dim3(256), 0, stream,
                     (const uint4*)x, (uint4*)Xb, (M * K) / 8,
                     (const uint4*)w, (uint4*)Wb, (N * K) / 8);

  const bool big_ok = (M % 256 == 0) && (N % 256 == 0) && (K % 256 == 0) &&
                      (((M / 256) * (N / 256)) % 8 == 0);
  if (big_ok) {
    hipLaunchKernelGGL(gemm256, dim3((M / 256) * (N / 256)), dim3(512), 0, stream,
                       Xb, Wb, b, out, M, N, K);
  } else {
    hipLaunchKernelGGL(gemm_bin, dim3(N / 128, M / 128), dim3(256), 0, stream,
                       Xb, Wb, b, out, M, N, K);
  }
}

// Round 6
// 145.393 us; speedup vs baseline: 1.4009x; 1.4009x over previous
//
#include <hip/hip_runtime.h>
#include <hip/hip_bf16.h>
#include <stdint.h>

typedef __bf16 bf16x8 __attribute__((ext_vector_type(8)));
typedef float  f32x16 __attribute__((ext_vector_type(16)));

// ---------- helpers ----------

__device__ __forceinline__ uint32_t rn2_bf16(uint32_t lo, uint32_t hi) {
  uint32_t rlo = (lo + 0x7FFFu + ((lo >> 16) & 1u)) >> 16;
  uint32_t rhi = (hi + 0x7FFFu + ((hi >> 16) & 1u)) >> 16;
  return (rhi << 16) | (rlo & 0xFFFFu);
}

__device__ __forceinline__ uint32_t sign2_bf16(uint32_t lo, uint32_t hi) {
  uint32_t slo = (lo & 0x7FFFFFFFu) ? (0x3F80u | ((lo >> 16) & 0x8000u)) : 0u;
  uint32_t shi = (hi & 0x7FFFFFFFu) ? (0x3F80u | ((hi >> 16) & 0x8000u)) : 0u;
  return (shi << 16) | slo;
}

__device__ __forceinline__ void gl16(const void* g, void* l) {
  __builtin_amdgcn_global_load_lds(
      (const __attribute__((address_space(1))) uint32_t*)g,
      (__attribute__((address_space(3))) uint32_t*)l,
      16, 0, 0);
}

// ---------- prep: f32 row-major -> bf16 FRAGMENT-TILE layout ----------
// Fragment-tile layout (per matrix, rows R, cols K):
//   16B chunk index = ((kt*(R/32)+mb)*4 + ks)*64 + sub*32 + r
// holds rows[mb*32+r], k = kt*64 + ks*16 + sub*8 .. +8  (8 bf16 = 16B).
// This makes each GEMM block's per-K-tile operand a contiguous 32KB region
// (8 mb-planes x 4KB), so global_load_lds staging is fully coalesced, and
// equals the MFMA 32x32x16 operand layout (R5-verified) at lane*16B.
// Thread mapping: virtual wave = 8 rows x 8 k8-chunks -> reads are 8x256B
// segments, writes are 8x128B segments (both HBM-efficient).

__global__ void prep_frag(const float* __restrict__ x, uint4* __restrict__ xf, int Mx,
                          const float* __restrict__ w, uint4* __restrict__ wf, int Nw,
                          int K) {
  const int kpw = K >> 6;  // 8-chunk k8-groups per 8-row band
  const long nxc = ((long)Mx * K) >> 3;
  const long nwc = ((long)Nw * K) >> 3;
  const long stride = (long)gridDim.x * blockDim.x;
  for (long c = (long)blockIdx.x * blockDim.x + threadIdx.x; c < nxc + nwc; c += stride) {
    const bool isX = (c < nxc);
    const float* src = isX ? x : w;
    uint4* dst = isX ? xf : wf;
    const int rows32 = (isX ? Mx : Nw) >> 5;
    const long cc = isX ? c : (c - nxc);

    const int t = (int)(cc & 63);
    const long wv = cc >> 6;
    const int band = (int)(wv / kpw);
    const int kg = (int)(wv % kpw);
    const int row = band * 8 + (t & 7);
    const int k8 = kg * 8 + (t >> 3);

    const int kt = k8 >> 3, ks = (k8 >> 1) & 3, sub = k8 & 1;
    const int mb = row >> 5, r = row & 31;
    const long out16 = ((long)(kt * rows32 + mb) * 4 + ks) * 64 + sub * 32 + r;

    const uint4* s = reinterpret_cast<const uint4*>(src + (long)row * K + k8 * 8);
    uint4 a = s[0], b = s[1];
    uint4 o;
    if (isX) {
      o.x = rn2_bf16(a.x, a.y); o.y = rn2_bf16(a.z, a.w);
      o.z = rn2_bf16(b.x, b.y); o.w = rn2_bf16(b.z, b.w);
    } else {
      o.x = sign2_bf16(a.x, a.y); o.y = sign2_bf16(a.z, a.w);
      o.z = sign2_bf16(b.x, b.y); o.w = sign2_bf16(b.z, b.w);
    }
    dst[out16] = o;
  }
}

// ---------- 256x256 GEMM, 32x32x16 MFMA, fragment-linear everything ----------
// C[M][N] = A[M][K] * B[N][K]^T + bias. BM=BN=256, BK=64, 8 waves (2Mx4N),
// wave tile 128x64. Operands pre-packed in fragment-tile order (prep_frag), so:
//  - staging = linear 16KB copies per STG (gl16, 64x16B contiguous per inst)
//  - LDS buf (64KB x2): A region 32KB = frag(mb0..7, ks0..3) at (mb*4+ks)*1024,
//    B region at +32768 ditto (nb over 256 cols); ds_read = base+lane*16+imm,
//    conflict-free by construction (R5: SQ_LDS_BANK_CONFLICT = 0).
// MFMA 32x32x16 operand/CD layouts as in R5 (correctness-verified there).
// Pipeline: 4 phases per K64-tile; phase = { MFMA(frags read last phase) ||
// ds_read next ks || staging STG } + raw s_barrier. VM0 at ph3/ph7 drains the
// tile staged 2-3 phases earlier (> HBM latency). Stage-after-read audit as R4.

#define BARX()  asm volatile("s_barrier" ::: "memory")
#define VM0()   asm volatile("s_waitcnt vmcnt(0)" ::: "memory")
#define VMN4()  asm volatile("s_waitcnt vmcnt(4)" ::: "memory")

__global__ __launch_bounds__(512, 2) void gemm256(
    const uint16_t* __restrict__ Af,  // fragment-tile bf16
    const uint16_t* __restrict__ Bf,  // fragment-tile sign bf16
    const float* __restrict__ bias,   // [N]
    float* __restrict__ C,            // [M][N] f32
    int M, int N, int K) {
  __shared__ alignas(16) uint8_t L[131072];
  uint8_t* Lb = L;

  const int tid  = threadIdx.x;
  const int lane = tid & 63;
  const int w    = tid >> 6;
  const int wr   = w >> 2;        // 0..1 -> M rows [wr*128, +128)
  const int wc   = w & 3;         // 0..3 -> N cols [wc*64, +64)
  const int l31  = lane & 31;
  const int lhi  = lane >> 5;

  // bijective XCD swizzle (nwg % 8 == 0 guaranteed by launcher)
  const int nbx = N >> 8;
  const int nwg = nbx * (M >> 8);
  const int bid = blockIdx.x;
  const int swb = (bid & 7) * (nwg >> 3) + (bid >> 3);
  const size_t m0 = (size_t)(swb / nbx) << 8;
  const size_t n0 = (size_t)(swb % nbx) << 8;

  const int NT = K >> 6;                       // number of K64 tiles
  const size_t ktA = (size_t)(M >> 5) * 4096;  // bytes per kt plane (A)
  const size_t ktB = (size_t)(N >> 5) * 4096;  // bytes per kt plane (B)
  const char* Abase = (const char*)Af + (m0 >> 5) * 4096;
  const char* Bbase = (const char*)Bf + (n0 >> 5) * 4096;

  const int wB = w << 11;            // wave's 2KB slice of a 16KB half
  const int g0 = wB + lane * 16;
  const int g1 = g0 + 1024;

#define STG(LOFF, SRC) do { \
    gl16((SRC) + g0, Lb + (LOFF) + wB); \
    gl16((SRC) + g1, Lb + (LOFF) + wB + 1024); } while (0)

  // fragment reads: linear, base + imm (A: mb=wr*4+i; B: nb=wc*2+j)
#define FRA32(d, i, q) (*reinterpret_cast<const bf16x8*>( \
    Lb + (d) * 65536 + wr * 16384 + (i) * 4096 + (q) * 1024 + lane * 16))
#define FRB32(d, j, q) (*reinterpret_cast<const bf16x8*>( \
    Lb + (d) * 65536 + 32768 + wc * 8192 + (j) * 4096 + (q) * 1024 + lane * 16))

#define RDA(DST, d, q) do { \
    _Pragma("unroll") \
    for (int i = 0; i < 4; ++i) DST[i] = FRA32(d, i, q); } while (0)
#define RDB(DST, d, q) do { \
    _Pragma("unroll") \
    for (int j = 0; j < 2; ++j) DST[j] = FRB32(d, j, q); } while (0)

  f32x16 acc[4][2] = {};

#define QM(A4, B2) do { \
    __builtin_amdgcn_s_setprio(1); \
    _Pragma("unroll") \
    for (int i = 0; i < 4; ++i) \
      _Pragma("unroll") \
      for (int j = 0; j < 2; ++j) \
        acc[i][j] = __builtin_amdgcn_mfma_f32_32x32x16_bf16( \
            A4[i], B2[j], acc[i][j], 0, 0, 0); \
    __builtin_amdgcn_s_setprio(0); } while (0)

  // ---- prologue: tile0 (A+B) -> buf0, tile1 B -> buf1 ----
  STG(0,      Abase);                 // A0 lo (mb 0-3)
  STG(16384,  Abase + 16384);         // A0 hi (mb 4-7)
  STG(32768,  Bbase);                 // B0 lo
  STG(49152,  Bbase + 16384);         // B0 hi
  STG(98304,  Bbase + ktB);           // B1 lo
  STG(114688, Bbase + ktB + 16384);   // B1 hi
  VMN4();   // tile0's 8 loads landed; B1's 4 still in flight
  BARX();

  bf16x8 aP[4], aQ[4], bP[2], bQ[2];
  RDA(aP, 0, 0);
  RDB(bP, 0, 0);

  const int T = K >> 7;  // iterations of 2 K-tiles
  for (int t = 0; t < T; ++t) {
    const int k2i = 2 * t + 2, k3i = 2 * t + 3;
    const char* A1 = Abase + (size_t)(2 * t + 1) * ktA;
    const char* A2 = Abase + (size_t)(k2i < NT ? k2i : NT - 1) * ktA;
    const char* B2 = Bbase + (size_t)(k2i < NT ? k2i : NT - 1) * ktB;
    const char* B3 = Bbase + (size_t)(k3i < NT ? k3i : NT - 1) * ktB;

    // ph1: MFMA buf0 ks0; read buf0 ks1; stage A(t1)->buf1-A
    QM(aP, bP);
    RDA(aQ, 0, 1); RDB(bQ, 0, 1);
    STG(65536, A1);
    STG(81920, A1 + 16384);
    BARX();

    // ph2: MFMA ks1; read ks2
    QM(aQ, bQ);
    RDA(aP, 0, 2); RDB(bP, 0, 2);
    BARX();

    // ph3: MFMA ks2; read ks3; VM0 drains t1 (B1@ph8-prev, A1@ph1)
    QM(aP, bP);
    RDA(aQ, 0, 3); RDB(bQ, 0, 3);
    VM0();
    BARX();

    // ph4: MFMA ks3; read buf1 ks0; stage B(t2)->buf0-B
    QM(aQ, bQ);
    RDA(aP, 1, 0); RDB(bP, 1, 0);
    STG(32768, B2);
    STG(49152, B2 + 16384);
    BARX();

    // ph5: MFMA buf1 ks0; read buf1 ks1; stage A(t2)->buf0-A
    QM(aP, bP);
    RDA(aQ, 1, 1); RDB(bQ, 1, 1);
    STG(0, A2);
    STG(16384, A2 + 16384);
    BARX();

    // ph6: MFMA ks1; read ks2
    QM(aQ, bQ);
    RDA(aP, 1, 2); RDB(bP, 1, 2);
    BARX();

    // ph7: MFMA ks2; read ks3; VM0 drains t2 (B@ph4, A@ph5)
    QM(aP, bP);
    RDA(aQ, 1, 3); RDB(bQ, 1, 3);
    VM0();
    BARX();

    // ph8: MFMA ks3; read buf0(t2) ks0; stage B(t3)->buf1-B
    QM(aQ, bQ);
    RDA(aP, 0, 0); RDB(bP, 0, 0);
    STG(98304, B3);
    STG(114688, B3 + 16384);
    BARX();
  }

  // ---- epilogue: +bias, f32 store ----
  // C/D 32x32: col = lane&31, row = (reg&3) + 8*(reg>>2) + 4*(lane>>5)
#pragma unroll
  for (int i = 0; i < 4; ++i) {
#pragma unroll
    for (int j2 = 0; j2 < 2; ++j2) {
      const size_t col = n0 + wc * 64 + j2 * 32 + l31;
      const float bv = bias[col];
      const size_t rbase = m0 + wr * 128 + i * 32 + lhi * 4;
#pragma unroll
      for (int r = 0; r < 16; ++r) {
        const size_t row = rbase + (r & 3) + 8 * (r >> 2);
        C[row * N + col] = acc[i][j2][r] + bv;
      }
    }
  }
}

// ---------- naive f32 fallback (shape mismatch only; never hit in harness) ----------
__global__ void gemm_naive(const float* __restrict__ x, const float* __restrict__ w,
                           const float* __restrict__ b, float* __restrict__ out,
                           int M, int N, int K) {
  int n = blockIdx.x * blockDim.x + threadIdx.x;
  int m = blockIdx.y;
  if (n >= N || m >= M) return;
  float acc = 0.f;
  for (int k = 0; k < K; ++k) {
    float wv = w[(size_t)n * K + k];
    float s = (wv > 0.f) ? 1.f : ((wv < 0.f) ? -1.f : 0.f);
    acc += x[(size_t)m * K + k] * s;
  }
  out[(size_t)m * N + n] = acc + b[n];
}

extern "C" void kernel_launch(void* const* d_in, const int* in_sizes, int n_in,
                              void* d_out, int out_size, void* d_ws, size_t ws_size,
                              hipStream_t stream) {
  const float* x = (const float*)d_in[0];
  const float* w = (const float*)d_in[1];
  const float* b = (const float*)d_in[2];
  float* out = (float*)d_out;

  const int N = in_sizes[2];
  const int K = in_sizes[1] / N;
  const int M = in_sizes[0] / K;

  const size_t need = ((size_t)M * K + (size_t)N * K) * sizeof(uint16_t);
  const bool big_ok = (M % 256 == 0) && (N % 256 == 0) && (K % 256 == 0) &&
                      (((M / 256) * (N / 256)) % 8 == 0) && (ws_size >= need);
  if (!big_ok) {
    hipLaunchKernelGGL(gemm_naive, dim3((N + 255) / 256, M), dim3(256), 0, stream,
                       x, w, b, out, M, N, K);
    return;
  }

  uint16_t* Xf = (uint16_t*)d_ws;
  uint16_t* Wf = Xf + (size_t)M * K;

  hipLaunchKernelGGL(prep_frag, dim3(2048), dim3(256), 0, stream,
                     x, (uint4*)Xf, M, w, (uint4*)Wf, N, K);

  hipLaunchKernelGGL(gemm256, dim3((M / 256) * (N / 256)), dim3(512), 0, stream,
                     Xf, Wf, b, out, M, N, K);
}